// Round 2
// baseline (88.792 us; speedup 1.0000x reference)
//
#include <hip/hip_runtime.h>

namespace {

constexpr int Bq = 32;    // batch
constexpr int Tq = 128;   // seq len == #scan steps (i) == softmax axis (t)
constexpr int Fq = 128;   // feature dim
constexpr int Uq = 128;   // unit dim
constexpr int PITCH = 132; // rows 16B-aligned; b128 row reads hit the 8-access/bank floor
constexpr int ITILE = 16;  // i per block

__device__ __forceinline__ float sigmoid_(float x) {
  return 1.0f / (1.0f + __expf(-x));
}
__device__ __forceinline__ float tanh_(float x) {
  x = fminf(20.0f, fmaxf(-20.0f, x));
  const float e = __expf(2.0f * x);
  return (e - 1.0f) / (e + 1.0f);
}

// ---------------------------------------------------------------------------
// Fully fused: logits -> softmax -> context -> gates -> activations.
//   L[t,i]  = sum_f X[b,t,f] * Wd[f,i]     (bd and carry s cancel in softmax)
//   alpha   = softmax_t(L)
//   C[i,f]  = sum_t alpha[t,i] * X[b,t,f]  (combined across t-halves in LDS)
//   z       = C @ Wk + bl  (gates i,c,o only; f-gate dead: c0=0; Wr dead: h0=0)
//   out[b,i,u] = sig(z_o) * tanh( sig(z_i) * tanh(z_c) )
//
// R5 restructure vs R4 (which was LDS-bound in phases 1+2):
//  * waves = 2 t-groups x 4 i-groups (4 i/wave, lane<->t over 64 t), so each
//    wave streams only HALF of X per phase: LDS read bytes/CU halve.
//  * pitch 129 -> 132: rows 16B-aligned, all X reads become ds_read_b128
//    (balanced banks: start bank 4*(row+slot) mod 32 -> 8 accesses/bank).
//  * Xt[f][t] transposed copy staged from coalesced L2 re-reads of X, so
//    phase 2 reads b128 rows too (transposed LDS write would 16-way conflict).
//  * alpha stays in registers: the (tg,ig) wave that computed alpha over its
//    64 t is the wave that consumes it in phase 2 via broadcast __shfl.
//    Softmax is combined across the two t-halves flash-style (m,s exchange).
//  * phase 3 (gate GEMM) unchanged: it sits at the f32 FMA floor (~2.6us).
// grid(8, 32): x = i-tile (16 i), y = b. 512 threads = 8 waves, 1 block/CU.
// LDS: 66 + 66 + 8.25 KB + 256 B = 140.5 KB (< 160 KB, same occupancy as R4).
// ---------------------------------------------------------------------------
__global__ __launch_bounds__(512) void k_all(const float* __restrict__ X,
                                             const float* __restrict__ Wd,
                                             const float* __restrict__ Wk,
                                             const float* __restrict__ bl,
                                             float* __restrict__ out) {
  __shared__ float Xs[Tq * PITCH];      // [t][f]  66.0 KB
  __shared__ float Xt[Fq * PITCH];      // [f][t]  66.0 KB
  __shared__ float Cs[ITILE * PITCH];   //  8.25 KB
  __shared__ float SmM[2][ITILE];       // per-t-group softmax max
  __shared__ float SmS[2][ITILE];       // per-t-group softmax sum
  const int tid = threadIdx.x;
  const int b = blockIdx.y;
  const int i0b = blockIdx.x * ITILE;
  const float* Xb = X + b * (Tq * Fq);

  // ---- stage Xs[t][f] (float4, aligned: 132*4 = 528 = 33*16) ----
#pragma unroll
  for (int it = 0; it < 8; ++it) {
    const int e = tid + it * 512;
    const int t = e >> 5;                // 32 float4 per 128-float row
    const int f4 = e & 31;
    const float4 v = reinterpret_cast<const float4*>(Xb)[e];
    *reinterpret_cast<float4*>(&Xs[t * PITCH + f4 * 4]) = v;
  }
  // ---- stage Xt[f][t] from 4 coalesced dword re-reads (L1/L2 hit) ----
#pragma unroll
  for (int it = 0; it < 8; ++it) {
    const int e = tid + it * 512;        // 4096 = 128 f * 32 t-quads
    const int f = e & 127;               // consecutive across lanes -> coalesced
    const int t4 = e >> 7;               // wave-uniform
    float4 v;
    v.x = Xb[(t4 * 4 + 0) * Fq + f];
    v.y = Xb[(t4 * 4 + 1) * Fq + f];
    v.z = Xb[(t4 * 4 + 2) * Fq + f];
    v.w = Xb[(t4 * 4 + 3) * Fq + f];
    *reinterpret_cast<float4*>(&Xt[f * PITCH + t4 * 4]) = v;
  }
  __syncthreads();

  const int lane = tid & 63;
  const int wv = tid >> 6;               // 0..7
  const int tg = wv >> 2;                // t-group: 0 -> t 0..63, 1 -> t 64..127
  const int ig = wv & 3;                 // i-group: 4 i per wave
  const int iL = ig * 4;                 // local i base
  const int i0 = __builtin_amdgcn_readfirstlane(i0b + iL);
  const int t = tg * 64 + lane;

  // ---- stage 1: logits a[j] = L[t, i0+j], b128 row reads + s_load weights ----
  float a[4] = {0.f, 0.f, 0.f, 0.f};
  const float* xr = &Xs[t * PITCH];
  const float* Wp = Wd + i0;             // Wd[f][i] at f*Tq + i (top F rows)
#pragma unroll 4
  for (int f4 = 0; f4 < 32; ++f4) {
    const float4 x = *reinterpret_cast<const float4*>(&xr[f4 * 4]);
#pragma unroll
    for (int k = 0; k < 4; ++k) {
      const float* wr = Wp + (f4 * 4 + k) * Tq;  // uniform -> s_load_dwordx4
      const float xv = (&x.x)[k];
#pragma unroll
      for (int j = 0; j < 4; ++j) a[j] = fmaf(xv, wr[j], a[j]);
    }
  }

  // ---- softmax over t: wave-local (64 t) reduce, then cross-t-group combine ----
  float m[4], e[4], s[4];
#pragma unroll
  for (int j = 0; j < 4; ++j) {
    float mw = a[j];
#pragma unroll
    for (int d = 1; d < 64; d <<= 1) mw = fmaxf(mw, __shfl_xor(mw, d, 64));
    const float ee = __expf(a[j] - mw);
    float ss = ee;
#pragma unroll
    for (int d = 1; d < 64; d <<= 1) ss += __shfl_xor(ss, d, 64);
    m[j] = mw; e[j] = ee; s[j] = ss;
  }
  if (lane == 0) {
#pragma unroll
    for (int j = 0; j < 4; ++j) {
      SmM[tg][iL + j] = m[j];
      SmS[tg][iL + j] = s[j];
    }
  }
  __syncthreads();
  float p[4];                            // alpha[t, i0+j] for this lane's t
#pragma unroll
  for (int j = 0; j < 4; ++j) {
    const float mo = SmM[tg ^ 1][iL + j];
    const float so = SmS[tg ^ 1][iL + j];
    const float gm = fmaxf(m[j], mo);
    const float sc = __expf(m[j] - gm);
    const float S = s[j] * sc + so * __expf(mo - gm);
    p[j] = e[j] * (sc / S);
  }

  // ---- stage 2: partial C[i,f] over this wave's 64 t; lanes <-> f.
  //      alpha comes from registers via broadcast shfl (no LDS round-trip). ----
  float c0[4] = {0.f, 0.f, 0.f, 0.f};   // f = lane
  float c1[4] = {0.f, 0.f, 0.f, 0.f};   // f = lane + 64
  const int tb = tg * 64;
  const float* xtr0 = &Xt[lane * PITCH + tb];
  const float* xtr1 = &Xt[(lane + 64) * PITCH + tb];
#pragma unroll 4
  for (int q = 0; q < 16; ++q) {
    const float4 x0 = *reinterpret_cast<const float4*>(&xtr0[q * 4]);
    const float4 x1 = *reinterpret_cast<const float4*>(&xtr1[q * 4]);
#pragma unroll
    for (int k = 0; k < 4; ++k) {
      const float xa = (&x0.x)[k];
      const float xb = (&x1.x)[k];
#pragma unroll
      for (int j = 0; j < 4; ++j) {
        const float aj = __shfl(p[j], q * 4 + k, 64);  // alpha[tb+q*4+k, i0+j]
        c0[j] = fmaf(aj, xa, c0[j]);
        c1[j] = fmaf(aj, xb, c1[j]);
      }
    }
  }
  // combine t-halves through Cs (distinct rows per ig -> no races)
  if (tg == 0) {
#pragma unroll
    for (int j = 0; j < 4; ++j) {
      Cs[(iL + j) * PITCH + lane] = c0[j];
      Cs[(iL + j) * PITCH + lane + 64] = c1[j];
    }
  }
  __syncthreads();
  if (tg == 1) {
#pragma unroll
    for (int j = 0; j < 4; ++j) {
      Cs[(iL + j) * PITCH + lane] += c0[j];
      Cs[(iL + j) * PITCH + lane + 64] += c1[j];
    }
  }
  __syncthreads();

  // ---- gate GEMM + activations (unchanged: at the f32 FMA floor).
  //      thread -> u = (wv&3)*32 + (lane&31);
  //                i-group ig3 = (wv>>2)*2 + (lane>>5): rows ig3*4..ig3*4+3 ----
  const int uu = lane & 31;
  const int ub = (wv & 3) * 32 + uu;
  const int ig3 = ((wv >> 2) << 1) | (lane >> 5);
  const int ih = ig3 * 4;
  float zi[4] = {0.f, 0.f, 0.f, 0.f};
  float zc[4] = {0.f, 0.f, 0.f, 0.f};
  float zo[4] = {0.f, 0.f, 0.f, 0.f};

  const float* WkP = Wk + ub;            // Wk[f][n] at f*4U + n
  for (int f = 0; f < Fq; f += 4) {
    float4 cr[4];
#pragma unroll
    for (int j = 0; j < 4; ++j)          // b128 broadcast (2 addrs/wave: free)
      cr[j] = *reinterpret_cast<const float4*>(&Cs[(ih + j) * PITCH + f]);
#pragma unroll
    for (int ff = 0; ff < 4; ++ff) {
      const float* wf = WkP + (f + ff) * (4 * Uq);
      const float wi = wf[0];            // coalesced dword loads (L2-resident)
      const float wc = wf[2 * Uq];
      const float wo = wf[3 * Uq];
#pragma unroll
      for (int j = 0; j < 4; ++j) {
        const float cv = (&cr[j].x)[ff];
        zi[j] = fmaf(cv, wi, zi[j]);
        zc[j] = fmaf(cv, wc, zc[j]);
        zo[j] = fmaf(cv, wo, zo[j]);
      }
    }
  }

  const float bi = bl[ub];
  const float bc = bl[2 * Uq + ub];
  const float bo = bl[3 * Uq + ub];
#pragma unroll
  for (int j = 0; j < 4; ++j) {
    const float cc = sigmoid_(zi[j] + bi) * tanh_(zc[j] + bc);
    const float h = sigmoid_(zo[j] + bo) * tanh_(cc);
    out[(b * Tq + i0b + ih + j) * Uq + ub] = h;
  }
}

}  // namespace

extern "C" void kernel_launch(void* const* d_in, const int* in_sizes, int n_in,
                              void* d_out, int out_size, void* d_ws, size_t ws_size,
                              hipStream_t stream) {
  const float* X  = (const float*)d_in[0];   // (B, T, F)
  const float* Wd = (const float*)d_in[1];   // (F+U, T); only rows [0,F) matter
  // d_in[2] = bd: constant along softmax axis -> cancels, unused
  const float* Wk = (const float*)d_in[3];   // (F, 4U)
  // d_in[4] = Wr: multiplied by h0 == 0 -> unused
  const float* bl = (const float*)d_in[5];   // (4U,)
  float* out = (float*)d_out;                // (B, T, U) fp32

  k_all<<<dim3(8, 32), 512, 0, stream>>>(X, Wd, Wk, bl, out);
}

// Round 3
// 86.476 us; speedup vs baseline: 1.0268x; 1.0268x over previous
//
#include <hip/hip_runtime.h>

namespace {

constexpr int Bq = 32;    // batch
constexpr int Tq = 128;   // seq len == #scan steps (i) == softmax axis (t)
constexpr int Fq = 128;   // feature dim
constexpr int Uq = 128;   // unit dim
constexpr int PITCH = 132; // rows 16B-aligned; b128 row reads hit the 8-access/bank floor
constexpr int ITILE = 16;  // i per block

__device__ __forceinline__ float sigmoid_(float x) {
  return 1.0f / (1.0f + __expf(-x));
}
__device__ __forceinline__ float tanh_(float x) {
  x = fminf(20.0f, fmaxf(-20.0f, x));
  const float e = __expf(2.0f * x);
  return (e - 1.0f) / (e + 1.0f);
}
// wave-uniform broadcast of a float from a compile-time lane -> SGPR.
// (R5 used __shfl, which is free to lower to ds_bpermute_b32: 256 extra
//  LDS-pipe insts/lane in phase 2 == the R5 regression. readlane is VALU.)
__device__ __forceinline__ float bcast_(float v, int lane) {
  return __uint_as_float(__builtin_amdgcn_readlane(__float_as_uint(v), lane));
}

// ---------------------------------------------------------------------------
// Fully fused: logits -> softmax -> context -> gates -> activations.
//   L[t,i]  = sum_f X[b,t,f] * Wd[f,i]     (bd and carry s cancel in softmax)
//   alpha   = softmax_t(L)
//   C[i,f]  = sum_t alpha[t,i] * X[b,t,f]  (combined across t-halves in LDS)
//   z       = C @ Wk + bl  (gates i,c,o only; f-gate dead: c0=0; Wr dead: h0=0)
//   out[b,i,u] = sig(z_o) * tanh( sig(z_i) * tanh(z_c) )
//
// R6 vs R5:
//  * alpha broadcast via v_readlane (SGPR operand of fmaf), NOT __shfl
//    (which could lower to ds_bpermute and flood the LDS pipe).
//  * late normalization: phase 2 accumulates with unnormalized e=exp(a-m_w);
//    the per-i scale exp(m-gm)/S is applied to c[] AFTER the loop, so the
//    cross-t-group softmax combine needs no barrier before phase 2.
//    Barriers: stage(1) + post-phase2(1) + Cs-combine(2) = 4 (R5: 5).
// Structure kept from R5: 2 t-groups x 4 i-groups (each wave streams half of
// X per phase), pitch 132 all-b128 LDS reads, Xt[f][t] transposed copy staged
// from coalesced L2 re-reads, phase 3 at the f32 FMA floor (~2.6us).
// grid(8, 32): x = i-tile (16 i), y = b. 512 threads = 8 waves, 1 block/CU.
// LDS: 66 + 66 + 8.25 KB + 256 B = 140.5 KB (< 160 KB).
// ---------------------------------------------------------------------------
__global__ __launch_bounds__(512) void k_all(const float* __restrict__ X,
                                             const float* __restrict__ Wd,
                                             const float* __restrict__ Wk,
                                             const float* __restrict__ bl,
                                             float* __restrict__ out) {
  __shared__ float Xs[Tq * PITCH];      // [t][f]  66.0 KB
  __shared__ float Xt[Fq * PITCH];      // [f][t]  66.0 KB
  __shared__ float Cs[ITILE * PITCH];   //  8.25 KB
  __shared__ float SmM[2][ITILE];       // per-t-group softmax max
  __shared__ float SmS[2][ITILE];       // per-t-group softmax sum
  const int tid = threadIdx.x;
  const int b = blockIdx.y;
  const int i0b = blockIdx.x * ITILE;
  const float* Xb = X + b * (Tq * Fq);

  // ---- stage Xs[t][f] (float4, aligned: 132*4 = 528 = 33*16) ----
#pragma unroll
  for (int it = 0; it < 8; ++it) {
    const int e = tid + it * 512;
    const int t = e >> 5;                // 32 float4 per 128-float row
    const int f4 = e & 31;
    const float4 v = reinterpret_cast<const float4*>(Xb)[e];
    *reinterpret_cast<float4*>(&Xs[t * PITCH + f4 * 4]) = v;
  }
  // ---- stage Xt[f][t] from 4 coalesced dword re-reads (L1/L2 hit) ----
#pragma unroll
  for (int it = 0; it < 8; ++it) {
    const int e = tid + it * 512;        // 4096 = 128 f * 32 t-quads
    const int f = e & 127;               // consecutive across lanes -> coalesced
    const int t4 = e >> 7;               // wave-uniform
    float4 v;
    v.x = Xb[(t4 * 4 + 0) * Fq + f];
    v.y = Xb[(t4 * 4 + 1) * Fq + f];
    v.z = Xb[(t4 * 4 + 2) * Fq + f];
    v.w = Xb[(t4 * 4 + 3) * Fq + f];
    *reinterpret_cast<float4*>(&Xt[f * PITCH + t4 * 4]) = v;
  }
  __syncthreads();

  const int lane = tid & 63;
  const int wv = tid >> 6;               // 0..7
  const int tg = wv >> 2;                // t-group: 0 -> t 0..63, 1 -> t 64..127
  const int ig = wv & 3;                 // i-group: 4 i per wave
  const int iL = ig * 4;                 // local i base
  const int i0 = __builtin_amdgcn_readfirstlane(i0b + iL);
  const int t = tg * 64 + lane;

  // ---- stage 1: logits a[j] = L[t, i0+j], b128 row reads + s_load weights ----
  float a[4] = {0.f, 0.f, 0.f, 0.f};
  const float* xr = &Xs[t * PITCH];
  const float* Wp = Wd + i0;             // Wd[f][i] at f*Tq + i (top F rows)
#pragma unroll 4
  for (int f4 = 0; f4 < 32; ++f4) {
    const float4 x = *reinterpret_cast<const float4*>(&xr[f4 * 4]);
#pragma unroll
    for (int k = 0; k < 4; ++k) {
      const float* wr = Wp + (f4 * 4 + k) * Tq;  // uniform -> s_load_dwordx4
      const float xv = (&x.x)[k];
#pragma unroll
      for (int j = 0; j < 4; ++j) a[j] = fmaf(xv, wr[j], a[j]);
    }
  }

  // ---- wave-local softmax stats over this t-group's 64 t.
  //      e stays UNNORMALIZED; the cross-t-group combine is deferred to after
  //      phase 2 (scale factors out of the t-sum), so no barrier stall here. ----
  float m[4], ev[4], s[4];
#pragma unroll
  for (int j = 0; j < 4; ++j) {
    float mw = a[j];
#pragma unroll
    for (int d = 1; d < 64; d <<= 1) mw = fmaxf(mw, __shfl_xor(mw, d, 64));
    const float ee = __expf(a[j] - mw);
    float ss = ee;
#pragma unroll
    for (int d = 1; d < 64; d <<= 1) ss += __shfl_xor(ss, d, 64);
    m[j] = mw; ev[j] = ee; s[j] = ss;
  }
  if (lane == 0) {
#pragma unroll
    for (int j = 0; j < 4; ++j) {
      SmM[tg][iL + j] = m[j];
      SmS[tg][iL + j] = s[j];
    }
  }

  // ---- stage 2: UNNORMALIZED partial C over this wave's 64 t; lanes <-> f.
  //      e comes from registers via v_readlane (VALU pipe, SGPR fma operand). ----
  float c0[4] = {0.f, 0.f, 0.f, 0.f};   // f = lane
  float c1[4] = {0.f, 0.f, 0.f, 0.f};   // f = lane + 64
  const int tb = tg * 64;
  const float* xtr0 = &Xt[lane * PITCH + tb];
  const float* xtr1 = &Xt[(lane + 64) * PITCH + tb];
#pragma unroll 4
  for (int q = 0; q < 16; ++q) {
    const float4 x0 = *reinterpret_cast<const float4*>(&xtr0[q * 4]);
    const float4 x1 = *reinterpret_cast<const float4*>(&xtr1[q * 4]);
#pragma unroll
    for (int k = 0; k < 4; ++k) {
      const float xa = (&x0.x)[k];
      const float xb = (&x1.x)[k];
#pragma unroll
      for (int j = 0; j < 4; ++j) {
        const float aj = bcast_(ev[j], q * 4 + k);  // e[tb+q*4+k, i0+j]
        c0[j] = fmaf(aj, xa, c0[j]);
        c1[j] = fmaf(aj, xb, c1[j]);
      }
    }
  }
  __syncthreads();                       // publishes SmM/SmS (written pre-phase2)

  // ---- cross-t-group softmax combine -> per-i scale; normalize c[] ----
#pragma unroll
  for (int j = 0; j < 4; ++j) {
    const float mo = SmM[tg ^ 1][iL + j];
    const float so = SmS[tg ^ 1][iL + j];
    const float gm = fmaxf(m[j], mo);
    const float sc = __expf(m[j] - gm);
    const float S = s[j] * sc + so * __expf(mo - gm);
    const float scale = sc / S;
    c0[j] *= scale;
    c1[j] *= scale;
  }

  // combine t-halves through Cs (distinct rows per ig -> no races)
  if (tg == 0) {
#pragma unroll
    for (int j = 0; j < 4; ++j) {
      Cs[(iL + j) * PITCH + lane] = c0[j];
      Cs[(iL + j) * PITCH + lane + 64] = c1[j];
    }
  }
  __syncthreads();
  if (tg == 1) {
#pragma unroll
    for (int j = 0; j < 4; ++j) {
      Cs[(iL + j) * PITCH + lane] += c0[j];
      Cs[(iL + j) * PITCH + lane + 64] += c1[j];
    }
  }
  __syncthreads();

  // ---- gate GEMM + activations (at the f32 FMA floor, ~2.6us/CU).
  //      thread -> u = (wv&3)*32 + (lane&31);
  //                i-group ig3 = (wv>>2)*2 + (lane>>5): rows ig3*4..ig3*4+3 ----
  const int uu = lane & 31;
  const int ub = (wv & 3) * 32 + uu;
  const int ig3 = ((wv >> 2) << 1) | (lane >> 5);
  const int ih = ig3 * 4;
  float zi[4] = {0.f, 0.f, 0.f, 0.f};
  float zc[4] = {0.f, 0.f, 0.f, 0.f};
  float zo[4] = {0.f, 0.f, 0.f, 0.f};

  const float* WkP = Wk + ub;            // Wk[f][n] at f*4U + n
  for (int f = 0; f < Fq; f += 4) {
    float4 cr[4];
#pragma unroll
    for (int j = 0; j < 4; ++j)          // b128 broadcast (2 addrs/wave: free)
      cr[j] = *reinterpret_cast<const float4*>(&Cs[(ih + j) * PITCH + f]);
#pragma unroll
    for (int ff = 0; ff < 4; ++ff) {
      const float* wf = WkP + (f + ff) * (4 * Uq);
      const float wi = wf[0];            // coalesced dword loads (L2-resident)
      const float wc = wf[2 * Uq];
      const float wo = wf[3 * Uq];
#pragma unroll
      for (int j = 0; j < 4; ++j) {
        const float cv = (&cr[j].x)[ff];
        zi[j] = fmaf(cv, wi, zi[j]);
        zc[j] = fmaf(cv, wc, zc[j]);
        zo[j] = fmaf(cv, wo, zo[j]);
      }
    }
  }

  const float bi = bl[ub];
  const float bc = bl[2 * Uq + ub];
  const float bo = bl[3 * Uq + ub];
#pragma unroll
  for (int j = 0; j < 4; ++j) {
    const float cc = sigmoid_(zi[j] + bi) * tanh_(zc[j] + bc);
    const float h = sigmoid_(zo[j] + bo) * tanh_(cc);
    out[(b * Tq + i0b + ih + j) * Uq + ub] = h;
  }
}

}  // namespace

extern "C" void kernel_launch(void* const* d_in, const int* in_sizes, int n_in,
                              void* d_out, int out_size, void* d_ws, size_t ws_size,
                              hipStream_t stream) {
  const float* X  = (const float*)d_in[0];   // (B, T, F)
  const float* Wd = (const float*)d_in[1];   // (F+U, T); only rows [0,F) matter
  // d_in[2] = bd: constant along softmax axis -> cancels, unused
  const float* Wk = (const float*)d_in[3];   // (F, 4U)
  // d_in[4] = Wr: multiplied by h0 == 0 -> unused
  const float* bl = (const float*)d_in[5];   // (4U,)
  float* out = (float*)d_out;                // (B, T, U) fp32

  k_all<<<dim3(8, 32), 512, 0, stream>>>(X, Wd, Wk, bl, out);
}